// Round 2
// baseline (95.983 us; speedup 1.0000x reference)
//
#include <hip/hip_runtime.h>

// SSIM map — fused 2-stage tile kernel, round-3: direct-from-global h-conv.
// B=16, C=3, H=W=512, 11-tap separable gaussian (sigma=1.5).
//
// Per 512-thread block: 32x64 output tile.
//   Stage 1+2 (merged): each item (74 rows x 8 col-groups = 592 items) loads
//            its 14-tap x/y windows STRAIGHT FROM GLOBAL (L1/L2-hot halo,
//            5x float4 aligned loads per array for interior blocks; predicated
//            scalar path for the 2 edge blocks in x), computes the horizontal
//            11-tap conv for 4 consecutive cols, writes float4(x,y,xx,yy) +
//            float(xy) to LDS.
//   Stage 3: vertical 11-tap conv; each thread computes 4 consecutive rows,
//            SSIM epilogue with v_rcp_f32, coalesced store.
// Rationale vs round-2: 74.3KB LDS (sbuf 25.5KB of it) capped occupancy at
// 2 blk/CU = 16 waves (41% measured) with no pipe >52% busy -> latency-bound.
// Dropping sbuf: LDS 49.7KB -> 3 blk/CU = 24 waves/CU, and only ONE barrier.
// hfx pitch padded to 36 so its 4-float row chunks are 16B-aligned (b128).
// Accumulation order identical to round-2 (bitwise-same output).

#define W    512
#define H    512
#define BC   48
#define TX   32
#define TY   64
#define IY   74          // TY + 10
#define HP   33          // hf4 pitch (float4)
#define HPX  36          // hfx pitch (float), 36*4B = 144B: 16B-aligned rows
#define NT   512

__global__ __launch_bounds__(NT) void ssim_kernel(
    const float* __restrict__ x, const float* __restrict__ y,
    float* __restrict__ out)
{
    __shared__ float4 hf4[IY][HP];    // 39072 B: h-conv (x,y,xx,yy)
    __shared__ float  hfx[IY][HPX];   // 10656 B: h-conv (xy)
                                      // total 49728 B -> 3 blocks/CU

    // fp32-normalized gaussian, sigma=1.5, K=11 (matches np reference ~1e-7)
    const float g[11] = {
        0.00102838f, 0.00759875f, 0.03600077f, 0.10936069f, 0.21300553f,
        0.26601172f,
        0.21300553f, 0.10936069f, 0.03600077f, 0.00759875f, 0.00102838f};

    const int tid = threadIdx.x;
    const int bc  = blockIdx.z;
    const int c0  = blockIdx.x * TX;
    const int r0  = blockIdx.y * TY;

    const float* __restrict__ xp = x + (size_t)bc * H * W;
    const float* __restrict__ yp = y + (size_t)bc * H * W;

    // interior in x: the aligned 20-float window [c0+cb-8, c0+cb+12) is fully
    // in-image for blockIdx.x in [1,14] (cols 24..487). Block-uniform branch.
    const bool interior = (blockIdx.x > 0) && (blockIdx.x < (W / TX) - 1);

    // ---- Stage 1+2: h-conv straight from global ----
    // item = row * 8 + colgroup; 74 rows x 8 groups = 592 items
#pragma unroll
    for (int it = 0; it < 2; ++it) {
        const int item = tid + it * NT;
        if (item < IY * 8) {
            const int row = item >> 3;
            const int cb  = (item & 7) << 2;     // base output col 0..28
            const int gr  = r0 - 5 + row;
            const bool rowok = (unsigned)gr < (unsigned)H;

            float vx[14], vy[14];
            if (interior) {
                // aligned window start: c0+cb-8 (== 0 mod 4); taps are
                // elements 3..16 of the 20-float window.
                float4 fx[5], fy[5];
                if (rowok) {
                    const size_t base = (size_t)gr * W + (c0 + cb - 8);
                    const float4* __restrict__ px4 =
                        reinterpret_cast<const float4*>(xp + base);
                    const float4* __restrict__ py4 =
                        reinterpret_cast<const float4*>(yp + base);
#pragma unroll
                    for (int q = 0; q < 5; ++q) { fx[q] = px4[q]; fy[q] = py4[q]; }
                } else {
#pragma unroll
                    for (int q = 0; q < 5; ++q) {
                        fx[q] = make_float4(0.f, 0.f, 0.f, 0.f);
                        fy[q] = make_float4(0.f, 0.f, 0.f, 0.f);
                    }
                }
#pragma unroll
                for (int kk = 0; kk < 14; ++kk) {
                    const int e = kk + 3;        // compile-time after unroll
                    const int q = e >> 2;
                    const int r = e & 3;
                    const float4 ax = fx[q];
                    const float4 ay = fy[q];
                    vx[kk] = (r == 0) ? ax.x : (r == 1) ? ax.y
                                              : (r == 2) ? ax.z : ax.w;
                    vy[kk] = (r == 0) ? ay.x : (r == 1) ? ay.y
                                              : (r == 2) ? ay.z : ay.w;
                }
            } else {
                const int gcb = c0 + cb - 5;
#pragma unroll
                for (int kk = 0; kk < 14; ++kk) {
                    const int gc = gcb + kk;
                    const bool ok = rowok && ((unsigned)gc < (unsigned)W);
                    float a = 0.f, b = 0.f;
                    if (ok) {
                        const size_t gi = (size_t)gr * W + gc;
                        a = xp[gi];
                        b = yp[gi];
                    }
                    vx[kk] = a;
                    vy[kk] = b;
                }
            }

            float a[4][5];
#pragma unroll
            for (int kk = 0; kk < 14; ++kk) {
                const float px  = vx[kk], py = vy[kk];
                const float pxx = px * px;
                const float pyy = py * py;
                const float pxy = px * py;
#pragma unroll
                for (int j = 0; j < 4; ++j) {
                    const int m = kk - j;        // tap index for output j
                    if (m >= 0 && m <= 10) {
                        const float w = g[m];
                        if (kk == j) {           // first tap: assign
                            a[j][0] = w * px;  a[j][1] = w * py;
                            a[j][2] = w * pxx; a[j][3] = w * pyy;
                            a[j][4] = w * pxy;
                        } else {
                            a[j][0] += w * px;  a[j][1] += w * py;
                            a[j][2] += w * pxx; a[j][3] += w * pyy;
                            a[j][4] += w * pxy;
                        }
                    }
                }
            }
#pragma unroll
            for (int j = 0; j < 4; ++j) {
                hf4[row][cb + j] = make_float4(a[j][0], a[j][1], a[j][2], a[j][3]);
                hfx[row][cb + j] = a[j][4];
            }
        }
    }
    __syncthreads();

    // ---- Stage 3: vertical conv + SSIM, 4 consecutive rows per thread ----
    {
        const int tx    = tid & 31;
        const int obase = (tid >> 5) << 2;       // first output row 0,4,..,60

        float acc[4][5];
#pragma unroll
        for (int rr = 0; rr < 14; ++rr) {
            const float4 h4 = hf4[obase + rr][tx];
            const float  h5 = hfx[obase + rr][tx];
#pragma unroll
            for (int j = 0; j < 4; ++j) {
                const int m = rr - j;            // tap index for output j
                if (m >= 0 && m <= 10) {
                    const float w = g[m];
                    if (rr == j) {
                        acc[j][0] = w * h4.x; acc[j][1] = w * h4.y;
                        acc[j][2] = w * h4.z; acc[j][3] = w * h4.w;
                        acc[j][4] = w * h5;
                    } else {
                        acc[j][0] += w * h4.x; acc[j][1] += w * h4.y;
                        acc[j][2] += w * h4.z; acc[j][3] += w * h4.w;
                        acc[j][4] += w * h5;
                    }
                }
            }
        }

        float* __restrict__ op = out + (size_t)bc * H * W;
#pragma unroll
        for (int j = 0; j < 4; ++j) {
            const float mu1   = acc[j][0];
            const float mu2   = acc[j][1];
            const float mu1sq = mu1 * mu1;
            const float mu2sq = mu2 * mu2;
            const float mu12  = mu1 * mu2;
            const float s1    = acc[j][2] - mu1sq;
            const float s2    = acc[j][3] - mu2sq;
            const float s12   = acc[j][4] - mu12;
            const float num = (2.f * mu12 + 1e-4f) * (2.f * s12 + 9e-4f);
            const float den = (mu1sq + mu2sq + 1e-4f) * (s1 + s2 + 9e-4f);
            op[(size_t)(r0 + obase + j) * W + c0 + tx] =
                num * __builtin_amdgcn_rcpf(den);
        }
    }
}

extern "C" void kernel_launch(void* const* d_in, const int* in_sizes, int n_in,
                              void* d_out, int out_size, void* d_ws, size_t ws_size,
                              hipStream_t stream) {
    const float* img_out    = (const float*)d_in[0];
    const float* img_target = (const float*)d_in[1];
    // d_in[2] is window_size==11; fixed by the problem, baked into the kernel.
    float* out = (float*)d_out;

    dim3 grid(W / TX, H / TY, BC);   // 16 x 8 x 48 = 6144 blocks
    ssim_kernel<<<grid, NT, 0, stream>>>(img_out, img_target, out);
}

// Round 4
// 76.349 us; speedup vs baseline: 1.2572x; 1.2572x over previous
//
#include <hip/hip_runtime.h>

// SSIM map — fused 3-stage tile kernel, round-4: aliased raw/h-conv LDS.
// (Round-3 bench failed on infra — UnresponsiveContainer before launch —
//  resubmission of the same kernel, aliasing logic re-audited.)
// B=16, C=3, H=W=512, 11-tap separable gaussian (sigma=1.5).
//
// Per 512-thread block: 32x64 output tile, ONE union LDS buffer [74][164]f:
//   raw phase: row r holds float2(x,y), words [2c, 2c+2), c=0..41
//   hf  phase: row r holds float4(hx,hy,hxx,hyy) at words [4c,4c+4) c=0..31
//              and hxy at word 128+c
// Aliasing is safe barrier-free: h-conv is row-local and the 8 items of a
// row are 8 consecutive lanes of ONE wave — every raw read of a row
// precedes (in wave program order, with register dependences) the hf writes
// to that row, and no other wave touches the row between the two barriers.
//
//   Stage 1: global -> LDS float2(x,y), 74x42 halo, zero-padded.  [barrier]
//   Stage 2: horizontal 11-tap conv; item = row*8+colgroup (592 items);
//            4 consecutive cols/thread from 14 register-cached taps;
//            writes hf4 + hfx OVER the same row's raw storage.      [barrier]
//   Stage 3: vertical 11-tap conv; 4 consecutive rows/thread; SSIM epilogue
//            with v_rcp_f32; coalesced store.
// Rationale vs round-2 (83.7us): 74.3KB LDS capped at 2 blk/CU = 16 waves
// (41% occ), no pipe >52% busy -> latency-bound. Union buffer: 48.5KB ->
// 3 blk/CU = 24 waves. Round-3's direct-global h-conv regressed (5x VMEM
// redundancy, L1 thrash) — staging through LDS is kept.
// Accumulation order identical to rounds 1-3 (bitwise-same output).

#define W     512
#define H     512
#define BC    48
#define TX    32
#define TY    64
#define IY    74          // TY + 10
#define PITCH 164         // floats/row: 656B, 16B-aligned, mod-32 = 4 words
#define NT    512

__global__ __launch_bounds__(NT) void ssim_kernel(
    const float* __restrict__ x, const float* __restrict__ y,
    float* __restrict__ out)
{
    __shared__ __align__(16) float buf[IY][PITCH];   // 48544 B -> 3 blocks/CU

    // fp32-normalized gaussian, sigma=1.5, K=11 (matches np reference ~1e-7)
    const float g[11] = {
        0.00102838f, 0.00759875f, 0.03600077f, 0.10936069f, 0.21300553f,
        0.26601172f,
        0.21300553f, 0.10936069f, 0.03600077f, 0.00759875f, 0.00102838f};

    const int tid = threadIdx.x;
    const int bc  = blockIdx.z;
    const int c0  = blockIdx.x * TX;
    const int r0  = blockIdx.y * TY;

    const float* __restrict__ xp = x + (size_t)bc * H * W;
    const float* __restrict__ yp = y + (size_t)bc * H * W;

    // ---- Stage 1: global -> LDS raw halo (74x42 float2), zero-padded ----
#pragma unroll
    for (int it = 0; it < 7; ++it) {
        const int idx = tid + it * NT;
        if (idx < IY * 42) {
            const int r  = idx / 42;
            const int c  = idx - r * 42;
            const int gr = r0 - 5 + r;
            const int gc = c0 - 5 + c;
            float vx = 0.f, vy = 0.f;
            if ((unsigned)gr < (unsigned)H && (unsigned)gc < (unsigned)W) {
                const size_t gi = (size_t)gr * W + gc;
                vx = xp[gi];
                vy = yp[gi];
            }
            *reinterpret_cast<float2*>(&buf[r][2 * c]) = make_float2(vx, vy);
        }
    }
    __syncthreads();

    // ---- Stage 2: horizontal conv, 4 consecutive cols per thread ----
    // item = row * 8 + colgroup; 74 rows x 8 groups = 592 items.
    // Row's 8 items are consecutive lanes of one wave -> safe in-row aliasing.
#pragma unroll
    for (int it = 0; it < 2; ++it) {
        const int item = tid + it * NT;
        if (item < IY * 8) {
            const int row = item >> 3;
            const int cb  = (item & 7) << 2;     // base output col 0..28

            float2 v[14];
#pragma unroll
            for (int kk = 0; kk < 14; ++kk)
                v[kk] = *reinterpret_cast<const float2*>(&buf[row][2 * (cb + kk)]);

            float a[4][5];
#pragma unroll
            for (int kk = 0; kk < 14; ++kk) {
                const float px  = v[kk].x, py = v[kk].y;
                const float pxx = px * px;
                const float pyy = py * py;
                const float pxy = px * py;
#pragma unroll
                for (int j = 0; j < 4; ++j) {
                    const int m = kk - j;        // tap index for output j
                    if (m >= 0 && m <= 10) {
                        const float w = g[m];
                        if (kk == j) {           // first tap: assign
                            a[j][0] = w * px;  a[j][1] = w * py;
                            a[j][2] = w * pxx; a[j][3] = w * pyy;
                            a[j][4] = w * pxy;
                        } else {
                            a[j][0] += w * px;  a[j][1] += w * py;
                            a[j][2] += w * pxx; a[j][3] += w * pyy;
                            a[j][4] += w * pxy;
                        }
                    }
                }
            }
            // hf4 over words [4cb, 4cb+16); hfx over words [128+cb, +4)
#pragma unroll
            for (int j = 0; j < 4; ++j) {
                *reinterpret_cast<float4*>(&buf[row][4 * (cb + j)]) =
                    make_float4(a[j][0], a[j][1], a[j][2], a[j][3]);
            }
            *reinterpret_cast<float4*>(&buf[row][128 + cb]) =
                make_float4(a[0][4], a[1][4], a[2][4], a[3][4]);
        }
    }
    __syncthreads();

    // ---- Stage 3: vertical conv + SSIM, 4 consecutive rows per thread ----
    {
        const int tx    = tid & 31;
        const int obase = (tid >> 5) << 2;       // first output row 0,4,..,60

        float acc[4][5];
#pragma unroll
        for (int rr = 0; rr < 14; ++rr) {
            const float4 h4 =
                *reinterpret_cast<const float4*>(&buf[obase + rr][4 * tx]);
            const float  h5 = buf[obase + rr][128 + tx];
#pragma unroll
            for (int j = 0; j < 4; ++j) {
                const int m = rr - j;            // tap index for output j
                if (m >= 0 && m <= 10) {
                    const float w = g[m];
                    if (rr == j) {
                        acc[j][0] = w * h4.x; acc[j][1] = w * h4.y;
                        acc[j][2] = w * h4.z; acc[j][3] = w * h4.w;
                        acc[j][4] = w * h5;
                    } else {
                        acc[j][0] += w * h4.x; acc[j][1] += w * h4.y;
                        acc[j][2] += w * h4.z; acc[j][3] += w * h4.w;
                        acc[j][4] += w * h5;
                    }
                }
            }
        }

        float* __restrict__ op = out + (size_t)bc * H * W;
#pragma unroll
        for (int j = 0; j < 4; ++j) {
            const float mu1   = acc[j][0];
            const float mu2   = acc[j][1];
            const float mu1sq = mu1 * mu1;
            const float mu2sq = mu2 * mu2;
            const float mu12  = mu1 * mu2;
            const float s1    = acc[j][2] - mu1sq;
            const float s2    = acc[j][3] - mu2sq;
            const float s12   = acc[j][4] - mu12;
            const float num = (2.f * mu12 + 1e-4f) * (2.f * s12 + 9e-4f);
            const float den = (mu1sq + mu2sq + 1e-4f) * (s1 + s2 + 9e-4f);
            op[(size_t)(r0 + obase + j) * W + c0 + tx] =
                num * __builtin_amdgcn_rcpf(den);
        }
    }
}

extern "C" void kernel_launch(void* const* d_in, const int* in_sizes, int n_in,
                              void* d_out, int out_size, void* d_ws, size_t ws_size,
                              hipStream_t stream) {
    const float* img_out    = (const float*)d_in[0];
    const float* img_target = (const float*)d_in[1];
    // d_in[2] is window_size==11; fixed by the problem, baked into the kernel.
    float* out = (float*)d_out;

    dim3 grid(W / TX, H / TY, BC);   // 16 x 8 x 48 = 6144 blocks
    ssim_kernel<<<grid, NT, 0, stream>>>(img_out, img_target, out);
}

// Round 5
// 74.664 us; speedup vs baseline: 1.2855x; 1.0226x over previous
//
#include <hip/hip_runtime.h>

// SSIM map — fused 3-stage tile kernel, round-5: conflict-free stage-2 lanes.
// B=16, C=3, H=W=512, 11-tap separable gaussian (sigma=1.5).
//
// Per 512-thread block: 32x64 output tile, ONE union LDS buffer [74][164]f:
//   raw phase: row r holds float2(x,y), words [2c, 2c+2), c=0..41
//   hf  phase: row r holds float4(hx,hy,hxx,hyy) at words [4c,4c+4) c=0..31
//              and hxy at word 128+c
//
// Round-5 change vs round-4 (76.3us, conflicts 1.43e7): stage-2 lane map was
// row=l>>3, cb=4*(l&7) -> hf4 write f4-slot mod 8 = (l>>3)+4(l&7): only 2
// residues per 8 lanes = 4-way bank conflict on all 4 b128 writes/item.
// NEW: row = 8*wave+(l&7), cb = 4*((l>>3)&7). With f4-pitch 41 (odd, ≡1 mod 8)
// every stage-2 pattern becomes distinct-mod-8 over 8-lane groups:
//   hf4 write: (l&7)+4c+j  -> conflict-free
//   raw read:  (l&7)+2c+q  -> conflict-free (and now 7x b128 instead of 14x b64)
//   hfx write: (l&7)+c     -> <=2-way (free)
// Wave-local aliasing preserved: wave w owns rows 8w..8w+7 (it=0), waves 0-1
// own rows 64-73 (it=1); whole-wave reads precede whole-wave writes in
// instruction order. Accumulation order identical (bitwise-same output).
//
//   Stage 1: global -> LDS float2(x,y), 74x42 halo, zero-padded.  [barrier]
//   Stage 2: horizontal 11-tap conv, 4 consecutive cols/thread.   [barrier]
//   Stage 3: vertical 11-tap conv, 4 consecutive rows/thread; SSIM epilogue
//            with v_rcp_f32; coalesced store.

#define W     512
#define H     512
#define BC    48
#define TX    32
#define TY    64
#define IY    74          // TY + 10
#define PITCH 164         // floats/row: 656B = 41 float4s (41 odd: bank stagger)
#define NT    512

__global__ __launch_bounds__(NT) void ssim_kernel(
    const float* __restrict__ x, const float* __restrict__ y,
    float* __restrict__ out)
{
    __shared__ __align__(16) float buf[IY][PITCH];   // 48544 B -> 3 blocks/CU

    // fp32-normalized gaussian, sigma=1.5, K=11 (matches np reference ~1e-7)
    const float g[11] = {
        0.00102838f, 0.00759875f, 0.03600077f, 0.10936069f, 0.21300553f,
        0.26601172f,
        0.21300553f, 0.10936069f, 0.03600077f, 0.00759875f, 0.00102838f};

    const int tid = threadIdx.x;
    const int bc  = blockIdx.z;
    const int c0  = blockIdx.x * TX;
    const int r0  = blockIdx.y * TY;

    const float* __restrict__ xp = x + (size_t)bc * H * W;
    const float* __restrict__ yp = y + (size_t)bc * H * W;

    // ---- Stage 1: global -> LDS raw halo (74x42 float2), zero-padded ----
#pragma unroll
    for (int it = 0; it < 7; ++it) {
        const int idx = tid + it * NT;
        if (idx < IY * 42) {
            const int r  = idx / 42;
            const int c  = idx - r * 42;
            const int gr = r0 - 5 + r;
            const int gc = c0 - 5 + c;
            float vx = 0.f, vy = 0.f;
            if ((unsigned)gr < (unsigned)H && (unsigned)gc < (unsigned)W) {
                const size_t gi = (size_t)gr * W + gc;
                vx = xp[gi];
                vy = yp[gi];
            }
            *reinterpret_cast<float2*>(&buf[r][2 * c]) = make_float2(vx, vy);
        }
    }
    __syncthreads();

    // ---- Stage 2: horizontal conv, 4 consecutive cols per thread ----
    // row = 8*(item>>6) + (item&7): wave-local rows, fast lane bits pick row.
    // cb  = 4*((item>>3)&7): colgroup from mid lane bits.
#pragma unroll
    for (int it = 0; it < 2; ++it) {
        const int item = tid + it * NT;
        const int row  = ((item >> 6) << 3) + (item & 7);
        const int cb   = ((item >> 3) & 7) << 2;     // base output col 0..28
        if (row < IY) {
            // raw: 7x ds_read_b128 over words [2cb, 2cb+28)
            float4 q4[7];
            const float* __restrict__ rbase = &buf[row][2 * cb];
#pragma unroll
            for (int q = 0; q < 7; ++q)
                q4[q] = *reinterpret_cast<const float4*>(rbase + 4 * q);

            float2 v[14];
#pragma unroll
            for (int kk = 0; kk < 14; ++kk) {
                const float4 f = q4[kk >> 1];        // compile-time after unroll
                v[kk] = (kk & 1) ? make_float2(f.z, f.w) : make_float2(f.x, f.y);
            }

            float a[4][5];
#pragma unroll
            for (int kk = 0; kk < 14; ++kk) {
                const float px  = v[kk].x, py = v[kk].y;
                const float pxx = px * px;
                const float pyy = py * py;
                const float pxy = px * py;
#pragma unroll
                for (int j = 0; j < 4; ++j) {
                    const int m = kk - j;        // tap index for output j
                    if (m >= 0 && m <= 10) {
                        const float w = g[m];
                        if (kk == j) {           // first tap: assign
                            a[j][0] = w * px;  a[j][1] = w * py;
                            a[j][2] = w * pxx; a[j][3] = w * pyy;
                            a[j][4] = w * pxy;
                        } else {
                            a[j][0] += w * px;  a[j][1] += w * py;
                            a[j][2] += w * pxx; a[j][3] += w * pyy;
                            a[j][4] += w * pxy;
                        }
                    }
                }
            }
            // hf4 over words [4cb, 4cb+16); hfx over words [128+cb, +4)
#pragma unroll
            for (int j = 0; j < 4; ++j) {
                *reinterpret_cast<float4*>(&buf[row][4 * (cb + j)]) =
                    make_float4(a[j][0], a[j][1], a[j][2], a[j][3]);
            }
            *reinterpret_cast<float4*>(&buf[row][128 + cb]) =
                make_float4(a[0][4], a[1][4], a[2][4], a[3][4]);
        }
    }
    __syncthreads();

    // ---- Stage 3: vertical conv + SSIM, 4 consecutive rows per thread ----
    {
        const int tx    = tid & 31;
        const int obase = (tid >> 5) << 2;       // first output row 0,4,..,60

        float acc[4][5];
#pragma unroll
        for (int rr = 0; rr < 14; ++rr) {
            const float4 h4 =
                *reinterpret_cast<const float4*>(&buf[obase + rr][4 * tx]);
            const float  h5 = buf[obase + rr][128 + tx];
#pragma unroll
            for (int j = 0; j < 4; ++j) {
                const int m = rr - j;            // tap index for output j
                if (m >= 0 && m <= 10) {
                    const float w = g[m];
                    if (rr == j) {
                        acc[j][0] = w * h4.x; acc[j][1] = w * h4.y;
                        acc[j][2] = w * h4.z; acc[j][3] = w * h4.w;
                        acc[j][4] = w * h5;
                    } else {
                        acc[j][0] += w * h4.x; acc[j][1] += w * h4.y;
                        acc[j][2] += w * h4.z; acc[j][3] += w * h4.w;
                        acc[j][4] += w * h5;
                    }
                }
            }
        }

        float* __restrict__ op = out + (size_t)bc * H * W;
#pragma unroll
        for (int j = 0; j < 4; ++j) {
            const float mu1   = acc[j][0];
            const float mu2   = acc[j][1];
            const float mu1sq = mu1 * mu1;
            const float mu2sq = mu2 * mu2;
            const float mu12  = mu1 * mu2;
            const float s1    = acc[j][2] - mu1sq;
            const float s2    = acc[j][3] - mu2sq;
            const float s12   = acc[j][4] - mu12;
            const float num = (2.f * mu12 + 1e-4f) * (2.f * s12 + 9e-4f);
            const float den = (mu1sq + mu2sq + 1e-4f) * (s1 + s2 + 9e-4f);
            op[(size_t)(r0 + obase + j) * W + c0 + tx] =
                num * __builtin_amdgcn_rcpf(den);
        }
    }
}

extern "C" void kernel_launch(void* const* d_in, const int* in_sizes, int n_in,
                              void* d_out, int out_size, void* d_ws, size_t ws_size,
                              hipStream_t stream) {
    const float* img_out    = (const float*)d_in[0];
    const float* img_target = (const float*)d_in[1];
    // d_in[2] is window_size==11; fixed by the problem, baked into the kernel.
    float* out = (float*)d_out;

    dim3 grid(W / TX, H / TY, BC);   // 16 x 8 x 48 = 6144 blocks
    ssim_kernel<<<grid, NT, 0, stream>>>(img_out, img_target, out);
}

// Round 6
// 66.631 us; speedup vs baseline: 1.4405x; 1.1206x over previous
//
#include <hip/hip_runtime.h>

// SSIM map — fused 3-stage tile kernel, round-6: packed-fp32 math core.
// B=16, C=3, H=W=512, 11-tap separable gaussian (sigma=1.5).
//
// Structure as round-5 (32x64 tile, 512 thr, union LDS [74][164]f, 2 barriers,
// wave-local raw->hf aliasing, conflict-free stage-2 lane map) plus:
//
// 1) v_pk_fma_f32 / v_pk_mul_f32 (CDNA VOP3P packed fp32, 2 FMA/instr):
//    channels (x,y) and (xx,yy) ride in float2 pairs through both conv
//    passes -> 5 scalar FMA/tap-out becomes 2 pk_fma + 1 fma, products
//    3 mul -> 1 pk_mul + 1 mul. Weights broadcast (w,w) via SGPR pair
//    ("s" constraint; 1 scalar operand per VALU instr is legal).
//    Zero-init + always-fma == old first-tap assign bitwise (fma(w,p,+0)
//    rounds once, operands non-negative).
// 2) Stage 1 loads float2 (aligned 44-col window, origin c0-6; origins even
//    so no float2 straddles the image edge -> single bounds check/pair):
//    1628 dual-loads / 4 iters vs 3108 scalar pairs / 7 iters; b128 LDS
//    writes. Stage-2 taps move to words 2cb+2..2cb+29 (8x ds_read_b128).
//
// Round-5 post-mortem: conflicts 1.43e7->9.4e6 but dur only -1.6us ->
// LDS conflicts were not the limiter; VALUBusy 61% vs ~25us math floor
// says VALU instruction count is. This round attacks instruction count.

#define W     512
#define H     512
#define BC    48
#define TX    32
#define TY    64
#define IY    74          // TY + 10
#define IC2   22          // float2 cols staged per row (44 cols: c0-6..c0+37)
#define PITCH 164         // floats/row: 656B = 41 float4s (odd: bank stagger)
#define NT    512

__device__ __forceinline__ float2 pk_mul2(float2 a, float2 b) {
    float2 d;
    asm("v_pk_mul_f32 %0, %1, %2" : "=v"(d) : "v"(a), "v"(b));
    return d;
}
// acc = w*v + acc  (both lanes); w uniform -> SGPR pair
__device__ __forceinline__ void pk_fma2(float2& acc, float2 w, float2 v) {
    asm("v_pk_fma_f32 %0, %1, %2, %0" : "+v"(acc) : "s"(w), "v"(v));
}

__global__ __launch_bounds__(NT) void ssim_kernel(
    const float* __restrict__ x, const float* __restrict__ y,
    float* __restrict__ out)
{
    __shared__ __align__(16) float buf[IY][PITCH];   // 48544 B -> 3 blocks/CU

    // fp32-normalized gaussian, sigma=1.5, K=11 (matches np reference ~1e-7)
    const float g[11] = {
        0.00102838f, 0.00759875f, 0.03600077f, 0.10936069f, 0.21300553f,
        0.26601172f,
        0.21300553f, 0.10936069f, 0.03600077f, 0.00759875f, 0.00102838f};

    const int tid = threadIdx.x;
    const int bc  = blockIdx.z;
    const int c0  = blockIdx.x * TX;
    const int r0  = blockIdx.y * TY;

    const float* __restrict__ xp = x + (size_t)bc * H * W;
    const float* __restrict__ yp = y + (size_t)bc * H * W;

    const bool xin = (blockIdx.x > 0) && (blockIdx.x < (W / TX) - 1);

    // ---- Stage 1: global float2 -> LDS interleaved (x0,y0,x1,y1) ----
    // item = r*22 + c2; col pair gc = c0-6+2*c2 (even, never straddles edge)
#pragma unroll
    for (int it = 0; it < 4; ++it) {
        const int idx = tid + it * NT;
        if (idx < IY * IC2) {
            const int r  = idx / IC2;
            const int c2 = idx - r * IC2;
            const int gr = r0 - 5 + r;
            const int gc = c0 - 6 + 2 * c2;
            const bool ok = ((unsigned)gr < (unsigned)H) &&
                            (xin || ((unsigned)gc < (unsigned)W));
            float2 lx = make_float2(0.f, 0.f), ly = lx;
            if (ok) {
                const size_t gi = ((size_t)gr << 9) + gc;
                lx = *reinterpret_cast<const float2*>(xp + gi);
                ly = *reinterpret_cast<const float2*>(yp + gi);
            }
            *reinterpret_cast<float4*>(&buf[r][4 * c2]) =
                make_float4(lx.x, ly.x, lx.y, ly.y);
        }
    }
    __syncthreads();

    // ---- Stage 2: horizontal conv, 4 consecutive cols per thread ----
    // row = 8*wave+(l&7) (wave-local rows), cb = 4*((l>>3)&7).
    // Taps for outputs cb..cb+3: local cols cb+1..cb+14 = words 2cb+2..2cb+29.
#pragma unroll
    for (int it = 0; it < 2; ++it) {
        const int item = tid + it * NT;
        const int row  = ((item >> 6) << 3) + (item & 7);
        const int cb   = ((item >> 3) & 7) << 2;     // base output col 0..28
        if (row < IY) {
            float4 q4[8];
            const float* __restrict__ rb = &buf[row][2 * cb];
#pragma unroll
            for (int q = 0; q < 8; ++q)
                q4[q] = *reinterpret_cast<const float4*>(rb + 4 * q);

            float2 A01[4], A23[4];
            float  A4[4];
#pragma unroll
            for (int j = 0; j < 4; ++j) {
                A01[j] = make_float2(0.f, 0.f);
                A23[j] = make_float2(0.f, 0.f);
                A4[j]  = 0.f;
            }
#pragma unroll
            for (int kk = 0; kk < 14; ++kk) {
                const float4 f = q4[(kk + 1) >> 1];  // compile-time after unroll
                const float2 vv = (kk & 1) ? make_float2(f.x, f.y)
                                           : make_float2(f.z, f.w);
                const float2 pp  = pk_mul2(vv, vv);  // (xx, yy)
                const float  pxy = vv.x * vv.y;
#pragma unroll
                for (int j = 0; j < 4; ++j) {
                    const int m = kk - j;            // tap index for output j
                    if (m >= 0 && m <= 10) {
                        const float2 w2 = make_float2(g[m], g[m]);
                        pk_fma2(A01[j], w2, vv);
                        pk_fma2(A23[j], w2, pp);
                        A4[j] = fmaf(g[m], pxy, A4[j]);
                    }
                }
            }
            // hf4 over words [4cb, 4cb+16); hfx over words [128+cb, +4)
#pragma unroll
            for (int j = 0; j < 4; ++j) {
                *reinterpret_cast<float4*>(&buf[row][4 * (cb + j)]) =
                    make_float4(A01[j].x, A01[j].y, A23[j].x, A23[j].y);
            }
            *reinterpret_cast<float4*>(&buf[row][128 + cb]) =
                make_float4(A4[0], A4[1], A4[2], A4[3]);
        }
    }
    __syncthreads();

    // ---- Stage 3: vertical conv + SSIM, 4 consecutive rows per thread ----
    {
        const int tx    = tid & 31;
        const int obase = (tid >> 5) << 2;       // first output row 0,4,..,60

        float2 acc01[4], acc23[4];
        float  acc4[4];
#pragma unroll
        for (int j = 0; j < 4; ++j) {
            acc01[j] = make_float2(0.f, 0.f);
            acc23[j] = make_float2(0.f, 0.f);
            acc4[j]  = 0.f;
        }
#pragma unroll
        for (int rr = 0; rr < 14; ++rr) {
            const float4 h4 =
                *reinterpret_cast<const float4*>(&buf[obase + rr][4 * tx]);
            const float  h5 = buf[obase + rr][128 + tx];
            const float2 h01 = make_float2(h4.x, h4.y);
            const float2 h23 = make_float2(h4.z, h4.w);
#pragma unroll
            for (int j = 0; j < 4; ++j) {
                const int m = rr - j;            // tap index for output j
                if (m >= 0 && m <= 10) {
                    const float2 w2 = make_float2(g[m], g[m]);
                    pk_fma2(acc01[j], w2, h01);
                    pk_fma2(acc23[j], w2, h23);
                    acc4[j] = fmaf(g[m], h5, acc4[j]);
                }
            }
        }

        float* __restrict__ op = out + (size_t)bc * H * W;
#pragma unroll
        for (int j = 0; j < 4; ++j) {
            const float mu1   = acc01[j].x;
            const float mu2   = acc01[j].y;
            const float mu1sq = mu1 * mu1;
            const float mu2sq = mu2 * mu2;
            const float mu12  = mu1 * mu2;
            const float s1    = acc23[j].x - mu1sq;
            const float s2    = acc23[j].y - mu2sq;
            const float s12   = acc4[j]    - mu12;
            const float num = (2.f * mu12 + 1e-4f) * (2.f * s12 + 9e-4f);
            const float den = (mu1sq + mu2sq + 1e-4f) * (s1 + s2 + 9e-4f);
            op[(size_t)(r0 + obase + j) * W + c0 + tx] =
                num * __builtin_amdgcn_rcpf(den);
        }
    }
}

extern "C" void kernel_launch(void* const* d_in, const int* in_sizes, int n_in,
                              void* d_out, int out_size, void* d_ws, size_t ws_size,
                              hipStream_t stream) {
    const float* img_out    = (const float*)d_in[0];
    const float* img_target = (const float*)d_in[1];
    // d_in[2] is window_size==11; fixed by the problem, baked into the kernel.
    float* out = (float*)d_out;

    dim3 grid(W / TX, H / TY, BC);   // 16 x 8 x 48 = 6144 blocks
    ssim_kernel<<<grid, NT, 0, stream>>>(img_out, img_target, out);
}

// Round 7
// 65.755 us; speedup vs baseline: 1.4597x; 1.0133x over previous
//
#include <hip/hip_runtime.h>

// SSIM map — fused 3-stage tile kernel, round-7: 8-col stage-2 items,
// float4 stage-1, packed epilogue.
// B=16, C=3, H=W=512, 11-tap separable gaussian (sigma=1.5).
//
// Structure as round-6 (32x64 tile, 512 thr, union LDS [74][164]f, 2 barriers,
// wave-local raw->hf aliasing, pk_fma math core) with:
//
// 1) Stage 1 loads float4 (aligned 48-col window, origin c0-8; origins are
//    multiples of 4 so no vector straddles the image edge): 888 items/2
//    passes vs 1628/4; 2x ds_write_b128 per item. Raw row = words 0..95.
// 2) Stage 2 items produce 8 consecutive cols: 18 taps / 8 outputs (products
//    amortized 2x), 10x ds_read_b128 (batched 5+5 to bound VGPR liveness),
//    296 items on waves 0-4 in ONE pass (waves 5-7 execz-skip).
//    Lane maps (f4-pitch 41 == 1 mod 8): raw read slot (l&7)+4cg+q,
//    hf4 write (l&7)+j, hfx (l&7)+2cg+h — all conflict-free mod 8.
//    Wave row ownership: wave w<4 owns rows 16w..16w+15; wave 4 rows 64-73.
// 3) Epilogue: pk_mul for (mu1^2,mu2^2), fma-folded num/den terms.
// __launch_bounds__(512,6): pin 6 waves/SIMD (=3 blocks/CU) VGPR target 84.
//
// Round-6 post-mortem: dur 74.7->66.6, VALUBusy flat ~65% -> still VALU-
// instruction-bound; HBM 2.6 TB/s (floor ~30us not binding). This round
// attacks per-wave instruction stream (~-9% stage2, -40% stage1).

#define W     512
#define H     512
#define BC    48
#define TX    32
#define TY    64
#define IY    74          // TY + 10
#define IC4   12          // float4 cols staged per row (48 cols: c0-8..c0+39)
#define PITCH 164         // floats/row: 656B = 41 float4s (odd: bank stagger)
#define NT    512

__device__ __forceinline__ float2 pk_mul2(float2 a, float2 b) {
    float2 d;
    asm("v_pk_mul_f32 %0, %1, %2" : "=v"(d) : "v"(a), "v"(b));
    return d;
}
// acc = w*v + acc  (both lanes); w uniform -> SGPR pair
__device__ __forceinline__ void pk_fma2(float2& acc, float2 w, float2 v) {
    asm("v_pk_fma_f32 %0, %1, %2, %0" : "+v"(acc) : "s"(w), "v"(v));
}

__global__ __launch_bounds__(NT, 6) void ssim_kernel(
    const float* __restrict__ x, const float* __restrict__ y,
    float* __restrict__ out)
{
    __shared__ __align__(16) float buf[IY][PITCH];   // 48544 B -> 3 blocks/CU

    // fp32-normalized gaussian, sigma=1.5, K=11 (matches np reference ~1e-7)
    const float g[11] = {
        0.00102838f, 0.00759875f, 0.03600077f, 0.10936069f, 0.21300553f,
        0.26601172f,
        0.21300553f, 0.10936069f, 0.03600077f, 0.00759875f, 0.00102838f};

    const int tid = threadIdx.x;
    const int bc  = blockIdx.z;
    const int c0  = blockIdx.x * TX;
    const int r0  = blockIdx.y * TY;

    const float* __restrict__ xp = x + (size_t)bc * H * W;
    const float* __restrict__ yp = y + (size_t)bc * H * W;

    const bool xin = (blockIdx.x > 0) && (blockIdx.x < (W / TX) - 1);

    // ---- Stage 1: global float4 -> LDS interleaved (x,y) pairs ----
    // item = r*12 + c4; cols gc = c0-8+4*c4 (aligned, never straddles edge)
#pragma unroll
    for (int it = 0; it < 2; ++it) {
        const int idx = tid + it * NT;
        if (idx < IY * IC4) {
            const int r  = idx / IC4;
            const int c4 = idx - r * IC4;
            const int gr = r0 - 5 + r;
            const int gc = c0 - 8 + 4 * c4;
            const bool ok = ((unsigned)gr < (unsigned)H) &&
                            (xin || ((unsigned)gc < (unsigned)W));
            float4 lx = make_float4(0.f, 0.f, 0.f, 0.f), ly = lx;
            if (ok) {
                const size_t gi = ((size_t)gr << 9) + gc;
                lx = *reinterpret_cast<const float4*>(xp + gi);
                ly = *reinterpret_cast<const float4*>(yp + gi);
            }
            *reinterpret_cast<float4*>(&buf[r][8 * c4]) =
                make_float4(lx.x, ly.x, lx.y, ly.y);
            *reinterpret_cast<float4*>(&buf[r][8 * c4 + 4]) =
                make_float4(lx.z, ly.z, lx.w, ly.w);
        }
    }
    __syncthreads();

    // ---- Stage 2: horizontal conv, 8 consecutive cols per item ----
    // wave w<4: rows 16w..16w+15 (lane: row-low = l&7, row-mid = l>>5,
    //           cg = (l>>3)&3); wave 4 (lanes 0-39): rows 64-73, cg = l&3.
    {
        const int l   = tid & 63;
        const int wid = tid >> 6;
        int row, cg;
        if (wid < 4) {
            row = (wid << 4) + ((l >> 5) << 3) + (l & 7);
            cg  = (l >> 3) & 3;
        } else {
            row = 64 + (l >> 2);
            cg  = l & 3;
        }
        const int  cb  = cg << 3;                  // base output col 0,8,16,24
        const bool act = (wid < 4) || ((wid == 4) && (l < 40));
        if (act) {
            // taps kk=0..17: local col cb+3+kk -> word 2cb+6+2kk;
            // b128 reads cover words 2cb+4 .. 2cb+43 (q = (kk+1)>>1).
            const float* __restrict__ rb = &buf[row][2 * cb + 4];

            float2 A01[8], A23[8];
            float  A4[8];
#pragma unroll
            for (int j = 0; j < 8; ++j) {
                A01[j] = make_float2(0.f, 0.f);
                A23[j] = make_float2(0.f, 0.f);
                A4[j]  = 0.f;
            }

            float4 q4[10];
#pragma unroll
            for (int q = 0; q < 5; ++q)            // batch A
                q4[q] = *reinterpret_cast<const float4*>(rb + 4 * q);
#pragma unroll
            for (int kk = 0; kk < 8; ++kk) {
                const float4 f = q4[(kk + 1) >> 1];
                const float2 vv = (kk & 1) ? make_float2(f.x, f.y)
                                           : make_float2(f.z, f.w);
                const float2 pp  = pk_mul2(vv, vv);
                const float  pxy = vv.x * vv.y;
#pragma unroll
                for (int j = 0; j < 8; ++j) {
                    const int m = kk - j;
                    if (m >= 0 && m <= 10) {
                        const float2 w2 = make_float2(g[m], g[m]);
                        pk_fma2(A01[j], w2, vv);
                        pk_fma2(A23[j], w2, pp);
                        A4[j] = fmaf(g[m], pxy, A4[j]);
                    }
                }
            }
#pragma unroll
            for (int q = 5; q < 10; ++q)           // batch B
                q4[q] = *reinterpret_cast<const float4*>(rb + 4 * q);
#pragma unroll
            for (int kk = 8; kk < 18; ++kk) {
                const float4 f = q4[(kk + 1) >> 1];
                const float2 vv = (kk & 1) ? make_float2(f.x, f.y)
                                           : make_float2(f.z, f.w);
                const float2 pp  = pk_mul2(vv, vv);
                const float  pxy = vv.x * vv.y;
#pragma unroll
                for (int j = 0; j < 8; ++j) {
                    const int m = kk - j;
                    if (m >= 0 && m <= 10) {
                        const float2 w2 = make_float2(g[m], g[m]);
                        pk_fma2(A01[j], w2, vv);
                        pk_fma2(A23[j], w2, pp);
                        A4[j] = fmaf(g[m], pxy, A4[j]);
                    }
                }
            }
            // hf4 at words 4*(cb+j); hfx at words 128+cb (two b128)
#pragma unroll
            for (int j = 0; j < 8; ++j) {
                *reinterpret_cast<float4*>(&buf[row][4 * (cb + j)]) =
                    make_float4(A01[j].x, A01[j].y, A23[j].x, A23[j].y);
            }
            *reinterpret_cast<float4*>(&buf[row][128 + cb]) =
                make_float4(A4[0], A4[1], A4[2], A4[3]);
            *reinterpret_cast<float4*>(&buf[row][128 + cb + 4]) =
                make_float4(A4[4], A4[5], A4[6], A4[7]);
        }
    }
    __syncthreads();

    // ---- Stage 3: vertical conv + SSIM, 4 consecutive rows per thread ----
    {
        const int tx    = tid & 31;
        const int obase = (tid >> 5) << 2;       // first output row 0,4,..,60

        float2 acc01[4], acc23[4];
        float  acc4[4];
#pragma unroll
        for (int j = 0; j < 4; ++j) {
            acc01[j] = make_float2(0.f, 0.f);
            acc23[j] = make_float2(0.f, 0.f);
            acc4[j]  = 0.f;
        }
#pragma unroll
        for (int rr = 0; rr < 14; ++rr) {
            const float4 h4 =
                *reinterpret_cast<const float4*>(&buf[obase + rr][4 * tx]);
            const float  h5 = buf[obase + rr][128 + tx];
            const float2 h01 = make_float2(h4.x, h4.y);
            const float2 h23 = make_float2(h4.z, h4.w);
#pragma unroll
            for (int j = 0; j < 4; ++j) {
                const int m = rr - j;            // tap index for output j
                if (m >= 0 && m <= 10) {
                    const float2 w2 = make_float2(g[m], g[m]);
                    pk_fma2(acc01[j], w2, h01);
                    pk_fma2(acc23[j], w2, h23);
                    acc4[j] = fmaf(g[m], h5, acc4[j]);
                }
            }
        }

        float* __restrict__ op = out + (size_t)bc * H * W;
#pragma unroll
        for (int j = 0; j < 4; ++j) {
            const float2 a01  = acc01[j];
            const float2 musq = pk_mul2(a01, a01);     // (mu1^2, mu2^2)
            const float  mu12 = a01.x * a01.y;
            const float  s1   = acc23[j].x - musq.x;
            const float  s2   = acc23[j].y - musq.y;
            const float  s12  = acc4[j]    - mu12;
            const float num = fmaf(2.f, mu12, 1e-4f) * fmaf(2.f, s12, 9e-4f);
            const float den = ((musq.x + musq.y) + 1e-4f) * ((s1 + s2) + 9e-4f);
            op[(size_t)(r0 + obase + j) * W + c0 + tx] =
                num * __builtin_amdgcn_rcpf(den);
        }
    }
}

extern "C" void kernel_launch(void* const* d_in, const int* in_sizes, int n_in,
                              void* d_out, int out_size, void* d_ws, size_t ws_size,
                              hipStream_t stream) {
    const float* img_out    = (const float*)d_in[0];
    const float* img_target = (const float*)d_in[1];
    // d_in[2] is window_size==11; fixed by the problem, baked into the kernel.
    float* out = (float*)d_out;

    dim3 grid(W / TX, H / TY, BC);   // 16 x 8 x 48 = 6144 blocks
    ssim_kernel<<<grid, NT, 0, stream>>>(img_out, img_target, out);
}